// Round 6
// baseline (79.357 us; speedup 1.0000x reference)
//
#include <hip/hip_runtime.h>

// QuantumLayer: 4-qubit, 4-layer VQC over batch B.
// R5: FOUR batch elements per thread = two independent v2f pipelines,
// interleaved per wire, to double per-wave ILP (R0 counters showed
// OccupancyPercent ~17% with VALUBusy ~72% -> per-wave dependency-bound).
// Layer loop rolled (#pragma unroll 1) for I$; M coeffs stay s_load/SGPR.
// State indexing: flat k = w0*8 + w1*4 + w2*2 + w3  (wire i -> bit (3-i)).

typedef float v2f __attribute__((ext_vector_type(2)));

// ---- Precompute M = RZ(pz)*RY(py) per (layer, wire). SU(2): alpha=M00,
// beta=M01; each of {ar,ai,br,bi} written twice (splatted). ----
__global__ void qlayer_precompute(const float* __restrict__ w, float* __restrict__ M) {
  int t = blockIdx.x * blockDim.x + threadIdx.x;
  if (t < 16) {
    int l = t >> 2, q = t & 3;
    float ay = 0.5f * w[8 * l + q];       // RY angle /2
    float az = 0.5f * w[8 * l + 4 + q];   // RZ angle /2
    float cy = cosf(ay), sy = sinf(ay);
    float cz = cosf(az), sz = sinf(az);
    float* m = M + t * 8;
    float ar = cz * cy, ai = -sz * cy, br = -cz * sy, bi = sz * sy;
    m[0] = ar; m[1] = ar;
    m[2] = ai; m[3] = ai;
    m[4] = br; m[5] = br;
    m[6] = bi; m[7] = bi;
  }
}

// G = M * RX(cx, sx) is SU(2): G = [[g, d], [-conj(d), conj(g)]].
__device__ __forceinline__ void make_g2(const v2f* __restrict__ M2, int idx,
                                        v2f cx, v2f sxv,
                                        v2f& gr, v2f& gi, v2f& dr, v2f& di) {
  v2f ar = M2[idx * 4 + 0], ai = M2[idx * 4 + 1];
  v2f br = M2[idx * 4 + 2], bi = M2[idx * 4 + 3];
  gr = ar * cx + bi * sxv;
  gi = ai * cx - br * sxv;
  dr = ai * sxv + br * cx;
  di = bi * cx - ar * sxv;
}

// Apply SU(2) gate [[g,d],[-conj(d),conj(g)]] on wire W (bit 3-W).
template <int W>
__device__ __forceinline__ void apply_su2(v2f (&sr)[16], v2f (&si)[16],
                                          v2f gr, v2f gi, v2f dr, v2f di) {
  constexpr int stride = 8 >> W;
#pragma unroll
  for (int base = 0; base < 16; base += 2 * stride) {
#pragma unroll
    for (int j = 0; j < stride; ++j) {
      const int k0 = base + j, k1 = k0 + stride;
      v2f a0r = sr[k0], a0i = si[k0], a1r = sr[k1], a1i = si[k1];
      sr[k0] = gr * a0r - gi * a0i + dr * a1r - di * a1i;
      si[k0] = gr * a0i + gi * a0r + dr * a1i + di * a1r;
      sr[k1] = gr * a1r + gi * a1i - dr * a0r - di * a0i;
      si[k1] = gr * a1i - gi * a1r - dr * a0i + di * a0r;
    }
  }
}

// CNOT(control C, target T): pure register permutation (fully unrolled).
template <int C, int T>
__device__ __forceinline__ void apply_cnot_(v2f (&sr)[16], v2f (&si)[16]) {
  constexpr int cb = 8 >> C, tb = 8 >> T;
#pragma unroll
  for (int k = 0; k < 16; ++k) {
    if ((k & cb) && !(k & tb)) {
      const int k2 = k | tb;
      v2f tr = sr[k]; sr[k] = sr[k2]; sr[k2] = tr;
      v2f ti = si[k]; si[k] = si[k2]; si[k2] = ti;
    }
  }
}

// Layer-0 in-place product build on |0000>, LSB-first.  bit=0 branch * g;
// bit=1 branch * -conj(d) = (-dr,+di): re = -dr*ar - di*ai, im = di*ar - dr*ai.
__device__ __forceinline__ void layer0_build(const v2f* __restrict__ M2,
                                             const v2f (&cx)[4], const v2f (&sx)[4],
                                             v2f (&sr)[16], v2f (&si)[16]) {
  v2f gr, gi, dr, di;
  make_g2(M2, 3, cx[3], sx[3], gr, gi, dr, di);
  sr[0] = gr;  si[0] = gi;
  sr[1] = -dr; si[1] = di;
  make_g2(M2, 2, cx[2], sx[2], gr, gi, dr, di);
#pragma unroll
  for (int k = 1; k >= 0; --k) {
    v2f ar_ = sr[k], ai_ = si[k];
    sr[k + 2] = -(dr * ar_) - di * ai_;
    si[k + 2] = di * ar_ - dr * ai_;
    sr[k]     = gr * ar_ - gi * ai_;
    si[k]     = gr * ai_ + gi * ar_;
  }
  make_g2(M2, 1, cx[1], sx[1], gr, gi, dr, di);
#pragma unroll
  for (int k = 3; k >= 0; --k) {
    v2f ar_ = sr[k], ai_ = si[k];
    sr[k + 4] = -(dr * ar_) - di * ai_;
    si[k + 4] = di * ar_ - dr * ai_;
    sr[k]     = gr * ar_ - gi * ai_;
    si[k]     = gr * ai_ + gi * ar_;
  }
  make_g2(M2, 0, cx[0], sx[0], gr, gi, dr, di);
#pragma unroll
  for (int k = 7; k >= 0; --k) {
    v2f ar_ = sr[k], ai_ = si[k];
    sr[k + 8] = -(dr * ar_) - di * ai_;
    si[k + 8] = di * ar_ - dr * ai_;
    sr[k]     = gr * ar_ - gi * ai_;
    si[k]     = gr * ai_ + gi * ar_;
  }
}

__device__ __forceinline__ void cnot_block(v2f (&sr)[16], v2f (&si)[16]) {
  apply_cnot_<2, 3>(sr, si);
  apply_cnot_<1, 2>(sr, si);
  apply_cnot_<0, 1>(sr, si);
  apply_cnot_<3, 0>(sr, si);
}

// Measurement butterfly: o_i = sum_k p_k * (bit(3-i)?-1:+1).
__device__ __forceinline__ void measure(const v2f (&sr)[16], const v2f (&si)[16],
                                        v2f& o0, v2f& o1, v2f& o2, v2f& o3) {
  v2f p[16];
#pragma unroll
  for (int k = 0; k < 16; ++k) p[k] = sr[k] * sr[k] + si[k] * si[k];
  v2f s2[8], d2[8];
#pragma unroll
  for (int k = 0; k < 8; ++k) { s2[k] = p[2 * k] + p[2 * k + 1]; d2[k] = p[2 * k] - p[2 * k + 1]; }
  o3 = ((d2[0] + d2[1]) + (d2[2] + d2[3])) + ((d2[4] + d2[5]) + (d2[6] + d2[7]));
  v2f s4[4], d4[4];
#pragma unroll
  for (int k = 0; k < 4; ++k) { s4[k] = s2[2 * k] + s2[2 * k + 1]; d4[k] = s2[2 * k] - s2[2 * k + 1]; }
  o2 = (d4[0] + d4[1]) + (d4[2] + d4[3]);
  v2f s8a = s4[0] + s4[1], s8b = s4[2] + s4[3];
  v2f d8a = s4[0] - s4[1], d8b = s4[2] - s4[3];
  o1 = d8a + d8b;
  o0 = s8a - s8b;
}

__global__ __launch_bounds__(256, 2) void qlayer_main(const float* __restrict__ x,
                                                      const v2f* __restrict__ M2,
                                                      float* __restrict__ out) {
  int t = blockIdx.x * blockDim.x + threadIdx.x;  // owns batch elems 4t..4t+3

  const float4* x4 = reinterpret_cast<const float4*>(x);
  float4 xa = x4[4 * t + 0], xb = x4[4 * t + 1];
  float4 xc = x4[4 * t + 2], xd = x4[4 * t + 3];

  v2f cxA[4], sxA[4], cxB[4], sxB[4];
  {
    float c, s;
    __sincosf(0.5f * xa.x, &s, &c); sxA[0].x = s; cxA[0].x = c;
    __sincosf(0.5f * xa.y, &s, &c); sxA[1].x = s; cxA[1].x = c;
    __sincosf(0.5f * xa.z, &s, &c); sxA[2].x = s; cxA[2].x = c;
    __sincosf(0.5f * xa.w, &s, &c); sxA[3].x = s; cxA[3].x = c;
    __sincosf(0.5f * xb.x, &s, &c); sxA[0].y = s; cxA[0].y = c;
    __sincosf(0.5f * xb.y, &s, &c); sxA[1].y = s; cxA[1].y = c;
    __sincosf(0.5f * xb.z, &s, &c); sxA[2].y = s; cxA[2].y = c;
    __sincosf(0.5f * xb.w, &s, &c); sxA[3].y = s; cxA[3].y = c;
    __sincosf(0.5f * xc.x, &s, &c); sxB[0].x = s; cxB[0].x = c;
    __sincosf(0.5f * xc.y, &s, &c); sxB[1].x = s; cxB[1].x = c;
    __sincosf(0.5f * xc.z, &s, &c); sxB[2].x = s; cxB[2].x = c;
    __sincosf(0.5f * xc.w, &s, &c); sxB[3].x = s; cxB[3].x = c;
    __sincosf(0.5f * xd.x, &s, &c); sxB[0].y = s; cxB[0].y = c;
    __sincosf(0.5f * xd.y, &s, &c); sxB[1].y = s; cxB[1].y = c;
    __sincosf(0.5f * xd.z, &s, &c); sxB[2].y = s; cxB[2].y = c;
    __sincosf(0.5f * xd.w, &s, &c); sxB[3].y = s; cxB[3].y = c;
  }

  v2f srA[16], siA[16], srB[16], siB[16];

  layer0_build(M2, cxA, sxA, srA, siA);
  layer0_build(M2, cxB, sxB, srB, siB);
  cnot_block(srA, siA);
  cnot_block(srB, siB);

#pragma unroll 1
  for (int l = 1; l < 4; ++l) {
    v2f gr, gi, dr, di;
    // wire 0 — pipeline A then B (independent chains interleave)
    make_g2(M2, l * 4 + 0, cxA[0], sxA[0], gr, gi, dr, di);
    apply_su2<0>(srA, siA, gr, gi, dr, di);
    make_g2(M2, l * 4 + 0, cxB[0], sxB[0], gr, gi, dr, di);
    apply_su2<0>(srB, siB, gr, gi, dr, di);
    // wire 1
    make_g2(M2, l * 4 + 1, cxA[1], sxA[1], gr, gi, dr, di);
    apply_su2<1>(srA, siA, gr, gi, dr, di);
    make_g2(M2, l * 4 + 1, cxB[1], sxB[1], gr, gi, dr, di);
    apply_su2<1>(srB, siB, gr, gi, dr, di);
    // wire 2
    make_g2(M2, l * 4 + 2, cxA[2], sxA[2], gr, gi, dr, di);
    apply_su2<2>(srA, siA, gr, gi, dr, di);
    make_g2(M2, l * 4 + 2, cxB[2], sxB[2], gr, gi, dr, di);
    apply_su2<2>(srB, siB, gr, gi, dr, di);
    // wire 3
    make_g2(M2, l * 4 + 3, cxA[3], sxA[3], gr, gi, dr, di);
    apply_su2<3>(srA, siA, gr, gi, dr, di);
    make_g2(M2, l * 4 + 3, cxB[3], sxB[3], gr, gi, dr, di);
    apply_su2<3>(srB, siB, gr, gi, dr, di);

    cnot_block(srA, siA);
    cnot_block(srB, siB);
  }

  v2f o0A, o1A, o2A, o3A, o0B, o1B, o2B, o3B;
  measure(srA, siA, o0A, o1A, o2A, o3A);
  measure(srB, siB, o0B, o1B, o2B, o3B);

  float4* o4 = reinterpret_cast<float4*>(out);
  o4[4 * t + 0] = make_float4(o0A.x, o1A.x, o2A.x, o3A.x);
  o4[4 * t + 1] = make_float4(o0A.y, o1A.y, o2A.y, o3A.y);
  o4[4 * t + 2] = make_float4(o0B.x, o1B.x, o2B.x, o3B.x);
  o4[4 * t + 3] = make_float4(o0B.y, o1B.y, o2B.y, o3B.y);
}

extern "C" void kernel_launch(void* const* d_in, const int* in_sizes, int n_in,
                              void* d_out, int out_size, void* d_ws, size_t ws_size,
                              hipStream_t stream) {
  const float* x = (const float*)d_in[0];
  const float* w = (const float*)d_in[1];
  float* out = (float*)d_out;
  float* M = (float*)d_ws;   // 128 floats used (splatted)
  int nb = in_sizes[0] / 4;
  int nt = nb / 4;           // 4 elements per thread; B=524288 -> nt=131072

  hipLaunchKernelGGL(qlayer_precompute, dim3(1), dim3(64), 0, stream, w, M);
  int blocks = nt / 256;     // exact: 512 blocks
  hipLaunchKernelGGL(qlayer_main, dim3(blocks), dim3(256), 0, stream,
                     x, (const v2f*)M, out);
}

// Round 7
// 75.757 us; speedup vs baseline: 1.0475x; 1.0475x over previous
//
#include <hip/hip_runtime.h>

// QuantumLayer: 4-qubit, 4-layer VQC over batch B.
// R6 = R4 structure (full unroll, 2 elems/thread in v2f -> v_pk_fma_f32) with:
//  1) precompute FUSED into main: threads 0-15 build the 16 splatted gate
//     coefficient quads in LDS (512 B), one barrier, ds_read_b64 per use.
//  2) layer-3 RZ dropped (exact: diagonal phase before final CNOT block is
//     probability-invariant).
// State indexing: flat k = w0*8 + w1*4 + w2*2 + w3  (wire i -> bit (3-i)).

typedef float v2f __attribute__((ext_vector_type(2)));

// G = M * RX(cx, sx) is SU(2): G = [[g, d], [-conj(d), conj(g)]].
// Msh entries are splatted v2f in LDS -> ds_read_b64 gives a VGPR pair that
// feeds VOP3P directly.
__device__ __forceinline__ void make_g2(const v2f* Msh, int idx,
                                        v2f cx, v2f sxv,
                                        v2f& gr, v2f& gi, v2f& dr, v2f& di) {
  v2f ar = Msh[idx * 4 + 0], ai = Msh[idx * 4 + 1];
  v2f br = Msh[idx * 4 + 2], bi = Msh[idx * 4 + 3];
  gr = ar * cx + bi * sxv;
  gi = ai * cx - br * sxv;
  dr = ai * sxv + br * cx;
  di = bi * cx - ar * sxv;
}

// Apply SU(2) gate [[g,d],[-conj(d),conj(g)]] on wire W (bit 3-W).
template <int W>
__device__ __forceinline__ void apply_su2(v2f (&sr)[16], v2f (&si)[16],
                                          v2f gr, v2f gi, v2f dr, v2f di) {
  constexpr int stride = 8 >> W;
#pragma unroll
  for (int base = 0; base < 16; base += 2 * stride) {
#pragma unroll
    for (int j = 0; j < stride; ++j) {
      const int k0 = base + j, k1 = k0 + stride;
      v2f a0r = sr[k0], a0i = si[k0], a1r = sr[k1], a1i = si[k1];
      sr[k0] = gr * a0r - gi * a0i + dr * a1r - di * a1i;
      si[k0] = gr * a0i + gi * a0r + dr * a1i + di * a1r;
      sr[k1] = gr * a1r + gi * a1i - dr * a0r - di * a0i;
      si[k1] = gr * a1i - gi * a1r - dr * a0i + di * a0r;
    }
  }
}

// CNOT(control C, target T): pure register permutation (fully unrolled).
template <int C, int T>
__device__ __forceinline__ void apply_cnot_(v2f (&sr)[16], v2f (&si)[16]) {
  constexpr int cb = 8 >> C, tb = 8 >> T;
#pragma unroll
  for (int k = 0; k < 16; ++k) {
    if ((k & cb) && !(k & tb)) {
      const int k2 = k | tb;
      v2f tr = sr[k]; sr[k] = sr[k2]; sr[k2] = tr;
      v2f ti = si[k]; si[k] = si[k2]; si[k2] = ti;
    }
  }
}

__global__ __launch_bounds__(256, 3) void qlayer_main(const float* __restrict__ x,
                                                      const float* __restrict__ w,
                                                      float* __restrict__ out) {
  // ---- Fused precompute: M = RZ(pz)*RY(py) per (layer, wire); layer 3 uses
  // RZ = I (exact, see header). Splatted v2f quads {ar,ai,br,bi} in LDS. ----
  __shared__ v2f Msh[16 * 4];
  int tid = threadIdx.x;
  if (tid < 16) {
    int l = tid >> 2, q = tid & 3;
    float ay = 0.5f * w[8 * l + q];                       // RY angle /2
    float az = (l == 3) ? 0.0f : 0.5f * w[8 * l + 4 + q]; // RZ angle /2 (I on l=3)
    float cy, sy, cz, sz;
    __sincosf(ay, &sy, &cy);
    __sincosf(az, &sz, &cz);
    float ar = cz * cy, ai = -sz * cy, br = -cz * sy, bi = sz * sy;
    Msh[tid * 4 + 0] = v2f{ar, ar};
    Msh[tid * 4 + 1] = v2f{ai, ai};
    Msh[tid * 4 + 2] = v2f{br, br};
    Msh[tid * 4 + 3] = v2f{bi, bi};
  }

  int t = blockIdx.x * blockDim.x + tid;  // owns batch elems 2t, 2t+1
  float4 xv0 = reinterpret_cast<const float4*>(x)[2 * t];
  float4 xv1 = reinterpret_cast<const float4*>(x)[2 * t + 1];
  v2f cx[4], sx[4];
  {
    float c, s;
    __sincosf(0.5f * xv0.x, &s, &c); sx[0].x = s; cx[0].x = c;
    __sincosf(0.5f * xv0.y, &s, &c); sx[1].x = s; cx[1].x = c;
    __sincosf(0.5f * xv0.z, &s, &c); sx[2].x = s; cx[2].x = c;
    __sincosf(0.5f * xv0.w, &s, &c); sx[3].x = s; cx[3].x = c;
    __sincosf(0.5f * xv1.x, &s, &c); sx[0].y = s; cx[0].y = c;
    __sincosf(0.5f * xv1.y, &s, &c); sx[1].y = s; cx[1].y = c;
    __sincosf(0.5f * xv1.z, &s, &c); sx[2].y = s; cx[2].y = c;
    __sincosf(0.5f * xv1.w, &s, &c); sx[3].y = s; cx[3].y = c;
  }

  __syncthreads();  // Msh ready

  v2f sr[16], si[16];

  // ---- Layer 0 on |0000>: product state, built IN-PLACE LSB-first.
  // bit=0 branch * g; bit=1 branch * -conj(d) = (-dr,+di):
  //   re = -dr*ar - di*ai,   im = di*ar - dr*ai. ----
  {
    v2f gr, gi, dr, di;
    make_g2(Msh, 3, cx[3], sx[3], gr, gi, dr, di);
    sr[0] = gr;  si[0] = gi;
    sr[1] = -dr; si[1] = di;
    make_g2(Msh, 2, cx[2], sx[2], gr, gi, dr, di);
#pragma unroll
    for (int k = 1; k >= 0; --k) {
      v2f ar_ = sr[k], ai_ = si[k];
      sr[k + 2] = -(dr * ar_) - di * ai_;
      si[k + 2] = di * ar_ - dr * ai_;
      sr[k]     = gr * ar_ - gi * ai_;
      si[k]     = gr * ai_ + gi * ar_;
    }
    make_g2(Msh, 1, cx[1], sx[1], gr, gi, dr, di);
#pragma unroll
    for (int k = 3; k >= 0; --k) {
      v2f ar_ = sr[k], ai_ = si[k];
      sr[k + 4] = -(dr * ar_) - di * ai_;
      si[k + 4] = di * ar_ - dr * ai_;
      sr[k]     = gr * ar_ - gi * ai_;
      si[k]     = gr * ai_ + gi * ar_;
    }
    make_g2(Msh, 0, cx[0], sx[0], gr, gi, dr, di);
#pragma unroll
    for (int k = 7; k >= 0; --k) {
      v2f ar_ = sr[k], ai_ = si[k];
      sr[k + 8] = -(dr * ar_) - di * ai_;
      si[k + 8] = di * ar_ - dr * ai_;
      sr[k]     = gr * ar_ - gi * ai_;
      si[k]     = gr * ai_ + gi * ar_;
    }
  }
  apply_cnot_<2, 3>(sr, si);
  apply_cnot_<1, 2>(sr, si);
  apply_cnot_<0, 1>(sr, si);
  apply_cnot_<3, 0>(sr, si);

  // ---- Layers 1..3 (fully unrolled: CNOTs stay register renames) ----
#pragma unroll
  for (int l = 1; l < 4; ++l) {
    v2f gr, gi, dr, di;
    make_g2(Msh, l * 4 + 0, cx[0], sx[0], gr, gi, dr, di);
    apply_su2<0>(sr, si, gr, gi, dr, di);
    make_g2(Msh, l * 4 + 1, cx[1], sx[1], gr, gi, dr, di);
    apply_su2<1>(sr, si, gr, gi, dr, di);
    make_g2(Msh, l * 4 + 2, cx[2], sx[2], gr, gi, dr, di);
    apply_su2<2>(sr, si, gr, gi, dr, di);
    make_g2(Msh, l * 4 + 3, cx[3], sx[3], gr, gi, dr, di);
    apply_su2<3>(sr, si, gr, gi, dr, di);
    apply_cnot_<2, 3>(sr, si);
    apply_cnot_<1, 2>(sr, si);
    apply_cnot_<0, 1>(sr, si);
    apply_cnot_<3, 0>(sr, si);
  }

  // ---- Measurement via butterfly tree: o_i = sum_k p_k * (bit(3-i)?-1:+1) ----
  v2f p[16];
#pragma unroll
  for (int k = 0; k < 16; ++k) p[k] = sr[k] * sr[k] + si[k] * si[k];
  v2f s2[8], d2[8];
#pragma unroll
  for (int k = 0; k < 8; ++k) { s2[k] = p[2 * k] + p[2 * k + 1]; d2[k] = p[2 * k] - p[2 * k + 1]; }
  v2f o3 = ((d2[0] + d2[1]) + (d2[2] + d2[3])) + ((d2[4] + d2[5]) + (d2[6] + d2[7]));
  v2f s4[4], d4[4];
#pragma unroll
  for (int k = 0; k < 4; ++k) { s4[k] = s2[2 * k] + s2[2 * k + 1]; d4[k] = s2[2 * k] - s2[2 * k + 1]; }
  v2f o2 = (d4[0] + d4[1]) + (d4[2] + d4[3]);
  v2f s8a = s4[0] + s4[1], s8b = s4[2] + s4[3];
  v2f d8a = s4[0] - s4[1], d8b = s4[2] - s4[3];
  v2f o1 = d8a + d8b;
  v2f o0 = s8a - s8b;

  float4* o4 = reinterpret_cast<float4*>(out);
  o4[2 * t]     = make_float4(o0.x, o1.x, o2.x, o3.x);
  o4[2 * t + 1] = make_float4(o0.y, o1.y, o2.y, o3.y);
}

extern "C" void kernel_launch(void* const* d_in, const int* in_sizes, int n_in,
                              void* d_out, int out_size, void* d_ws, size_t ws_size,
                              hipStream_t stream) {
  const float* x = (const float*)d_in[0];
  const float* w = (const float*)d_in[1];
  float* out = (float*)d_out;
  int nb = in_sizes[0] / 4;
  int np = nb / 2;           // 2 elements per thread; B=524288 -> np=262144

  int blocks = np / 256;     // exact: 1024 blocks
  hipLaunchKernelGGL(qlayer_main, dim3(blocks), dim3(256), 0, stream, x, w, out);
}